// Round 1
// baseline (369.431 us; speedup 1.0000x reference)
//
#include <hip/hip_runtime.h>

#define KK 16
#define DD 15          // K-1
#define NPIX (2048*2048)

__global__ __launch_bounds__(256) void gum_kernel(
    const float* __restrict__ z,      // (DD, NPIX)
    const float* __restrict__ vert,   // (KK, DD) row-major
    float* __restrict__ out)          // [0,NPIX) = X as float, [NPIX,2*NPIX) = dmin
{
    __shared__ float vT[DD * KK];     // [d][k] — broadcast reads
    __shared__ float vv[KK];

    const int t = threadIdx.x;
    if (t < DD * KK) {
        int k = t / DD, d = t % DD;
        vT[d * KK + k] = vert[t];
    }
    if (t < KK) {
        float s = 0.0f;
        #pragma unroll
        for (int d = 0; d < DD; ++d) {
            float v = vert[t * DD + d];
            s += v * v;
        }
        vv[t] = s;
    }
    __syncthreads();

    const int gid  = blockIdx.x * blockDim.x + t;  // pixel-group id (4 pixels)
    const int base = gid * 4;
    if (base >= NPIX) return;

    // 16 float4 accumulators for cross = v_k . z, plus zz
    float acc[KK][4];
    #pragma unroll
    for (int k = 0; k < KK; ++k)
        #pragma unroll
        for (int c = 0; c < 4; ++c) acc[k][c] = 0.0f;
    float zz[4] = {0.f, 0.f, 0.f, 0.f};

    #pragma unroll
    for (int d = 0; d < DD; ++d) {
        const float4 zd4 = *(const float4*)(z + (size_t)d * NPIX + base);
        const float zd[4] = {zd4.x, zd4.y, zd4.z, zd4.w};
        #pragma unroll
        for (int c = 0; c < 4; ++c) zz[c] += zd[c] * zd[c];
        #pragma unroll
        for (int k = 0; k < KK; ++k) {
            const float vdk = vT[d * KK + k];   // wave-uniform broadcast
            #pragma unroll
            for (int c = 0; c < 4; ++c) acc[k][c] += vdk * zd[c];
        }
    }

    float bestd[4];
    int   bestk[4];
    #pragma unroll
    for (int c = 0; c < 4; ++c) { bestd[c] = 3.0e38f; bestk[c] = 0; }

    #pragma unroll
    for (int k = 0; k < KK; ++k) {
        const float vvk = vv[k];
        #pragma unroll
        for (int c = 0; c < 4; ++c) {
            // match ref evaluation order: (zz - 2*cross) + vv
            float d2 = (zz[c] - 2.0f * acc[k][c]) + vvk;
            float dist = sqrtf(fmaxf(d2, 0.0f));
            if (dist < bestd[c]) { bestd[c] = dist; bestk[c] = k; }  // first-min tie-break
        }
    }

    float4 xo, dm;
    xo.x = (float)bestk[0]; xo.y = (float)bestk[1];
    xo.z = (float)bestk[2]; xo.w = (float)bestk[3];
    dm.x = bestd[0]; dm.y = bestd[1]; dm.z = bestd[2]; dm.w = bestd[3];

    *(float4*)(out + base)        = xo;
    *(float4*)(out + NPIX + base) = dm;
}

extern "C" void kernel_launch(void* const* d_in, const int* in_sizes, int n_in,
                              void* d_out, int out_size, void* d_ws, size_t ws_size,
                              hipStream_t stream) {
    const float* z    = (const float*)d_in[0];   // (15, 2048, 2048) fp32
    const float* vert = (const float*)d_in[1];   // (16, 15) fp32
    float* out = (float*)d_out;                  // 2 * NPIX floats

    const int npix    = in_sizes[0] / DD;        // 4194304
    const int threads = 256;
    const int groups  = npix / 4;                // 4 pixels per thread
    const int blocks  = (groups + threads - 1) / threads;  // 4096

    gum_kernel<<<blocks, threads, 0, stream>>>(z, vert, out);
}